// Round 9
// baseline (524.113 us; speedup 1.0000x reference)
//
#include <hip/hip_runtime.h>

#define LARGE_F 1e30f
#define LOG2E_F 1.4426950408889634f
#define LN2_F   0.6931471805599453f

constexpr int BB = 128;
constexpr int NN = 512;
constexpr int MM = 512;
constexpr int KK = 64;
constexpr int NDIAG = NN + MM - 1;   // 1023
constexpr int PCELLS = 263680;       // padded (4-float-aligned) cells per batch

// ---- 4-float-aligned antidiagonal slot layout -------------------------------
__device__ __forceinline__ int slot_off(int p) {
    if (p < NN) { const int a = p >> 2, r = p & 3; return ((a + 1) * (2 * a + r)) << 2; }
    const int t = p - NN, a = t >> 2, r = t & 3;
    return 132096 + (t << 9) - ((a * (2 * a + r - 1)) << 2);
}
__device__ __forceinline__ int imin4(int p) {
    return (p < NN) ? 0 : ((p - (NN - 1)) & ~3);
}
__device__ __forceinline__ int read_base(int p) { return slot_off(p) - imin4(p); }

// lane i <- lane i-1 via DPP wave_shr:1 (VALU). Lane 0 receives `bound`.
__device__ __forceinline__ float wave_shr1(float v, float bound) {
    const int r = __builtin_amdgcn_update_dpp(__float_as_int(bound), __float_as_int(v),
                                              0x138, 0xf, 0xf, false);
    return __int_as_float(r);
}

// ---------------- Phase 1: D[b,i,j] = ||x_i - y_j||^2 into aligned diag slots.
__global__ __launch_bounds__(256, 4) void sdtw_dist(const float* __restrict__ x,
                                                    const float* __restrict__ y,
                                                    float* __restrict__ Dws) {
    __shared__ float xs[64][68];
    __shared__ float ys[64][68];
    __shared__ float x2s[64];
    __shared__ float y2s[64];
    float (*dt)[66] = (float (*)[66])(&xs[0][0]);   // alias after k-loop

    const int b  = blockIdx.y;
    const int ti = (blockIdx.x >> 3) << 6;
    const int tj = (blockIdx.x & 7) << 6;
    const int t  = threadIdx.x;

    const float* xb = x + ((size_t)b * NN + ti) * KK;
    const float* yb = y + ((size_t)b * MM + tj) * KK;

    {
        const int r0 = t >> 4;
        const int c0 = (t & 15) << 2;
#pragma unroll
        for (int q = 0; q < 4; ++q) {
            const int r = r0 + (q << 4);
            const float4 xv = *(const float4*)(xb + r * KK + c0);
            const float4 yv = *(const float4*)(yb + r * KK + c0);
            *(float4*)(&xs[r][c0]) = xv;
            *(float4*)(&ys[r][c0]) = yv;
        }
    }
    __syncthreads();

    if (t < 128) {
        const int r = t & 63;
        const float* row = (t < 64) ? &xs[r][0] : &ys[r][0];
        float s = 0.f;
#pragma unroll
        for (int k = 0; k < KK; k += 4) {
            const float4 v = *(const float4*)(row + k);
            s = fmaf(v.x, v.x, s); s = fmaf(v.y, v.y, s);
            s = fmaf(v.z, v.z, s); s = fmaf(v.w, v.w, s);
        }
        if (t < 64) x2s[r] = s; else y2s[r] = s;
    }
    __syncthreads();

    const int ty = t >> 4;
    const int tx = t & 15;

    float acc[4][4] = {};
    for (int k0 = 0; k0 < KK; k0 += 4) {
        float4 xa[4], yv[4];
#pragma unroll
        for (int a = 0; a < 4; ++a) xa[a] = *(const float4*)(&xs[(a << 4) + ty][k0]);
#pragma unroll
        for (int c = 0; c < 4; ++c) yv[c] = *(const float4*)(&ys[(c << 4) + tx][k0]);
#pragma unroll
        for (int a = 0; a < 4; ++a) {
#pragma unroll
            for (int c = 0; c < 4; ++c) {
                acc[a][c] = fmaf(xa[a].x, yv[c].x, acc[a][c]);
                acc[a][c] = fmaf(xa[a].y, yv[c].y, acc[a][c]);
                acc[a][c] = fmaf(xa[a].z, yv[c].z, acc[a][c]);
                acc[a][c] = fmaf(xa[a].w, yv[c].w, acc[a][c]);
            }
        }
    }
    __syncthreads();

#pragma unroll
    for (int a = 0; a < 4; ++a) {
        const float xx = x2s[(a << 4) + ty];
#pragma unroll
        for (int c = 0; c < 4; ++c) {
            dt[(a << 4) + ty][(c << 4) + tx] = xx + y2s[(c << 4) + tx] - 2.f * acc[a][c];
        }
    }
    __syncthreads();

    {
        const int w    = t >> 6;
        const int lane = t & 63;
        float* Db = Dws + (size_t)b * PCELLS;
        for (int q = w; q < 127; q += 4) {
            const int i_lo = (q > 63) ? (q - 63) : 0;
            const int i_hi = (q < 63) ? q : 63;
            const int len  = i_hi - i_lo + 1;
            if (lane < len) {
                const int il = i_lo + lane;
                const int p  = ti + tj + q;
                Db[slot_off(p) + (ti + il) - imin4(p)] = dt[il][q - il];
            }
        }
    }
}

// ---------------- Phase 2: wavefront-pipelined DP. 8 waves; wave wv owns rows
// [64wv,64wv+63]; columns in 4 chunks of 128; 11 phases, ONE barrier per phase
// (vs 1023). Inside a chunk: 192-step intra-wave wavefront, neighbor row via
// DPP only; boundary row of the wave above preloaded into 2 lane-distributed
// VGPRs, consumed by lane0 via readlane (zero memory in the step chain).
// D via depth-16 register ring (refill per step, sched_barrier(0)-pinned;
// barriers never drain vmcnt). Ramp/drain lanes compute garbage that provably
// never reaches a valid cell.
__global__ __launch_bounds__(512, 1) void sdtw_dp(const float* __restrict__ Dws,
                                                  float* __restrict__ out) {
    __shared__ float hnd[2][8][132];     // [chunk parity][producer wave][0..128]
    const int b    = blockIdx.x;
    const int tid  = threadIdx.x;        // global row
    const int lane = tid & 63;
    const int wv   = tid >> 6;
    const float* __restrict__ Db = Dws + (size_t)b * PCELLS;

    const bool haveup = (wv > 0);
    const bool l0     = (lane == 0);

    float cur = LARGE_F;
    float carry = LARGE_F;               // R[row][chunk_left - 1]
    float nw = LARGE_F;

#pragma unroll 1
    for (int phase = 0; phase < 11; ++phase) {
        const int c = phase - wv;
        if (0 <= c && c < 4) {
            const int par = c & 1;
            // Boundary row from wave above (written last phase).
            float hA = LARGE_F, hB = LARGE_F, h0f = LARGE_F;
            if (haveup) {
                hA  = hnd[par][wv - 1][1 + lane];    // cols 128c + 0..63
                hB  = hnd[par][wv - 1][65 + lane];   // cols 128c + 64..127
                h0f = hnd[par][wv - 1][0];           // col 128c - 1
            }
            // Publish my carry as next wave's col-(128c-1) value.
            if (lane == 63) hnd[par][wv][0] = carry;
            // nw init = R[row-1][128c-1]: lane l <- lane l-1's carry;
            // lane0 <- h0f / LARGE; global corner (0,0): 0.
            const float bnd = haveup ? h0f : ((c == 0) ? 0.f : LARGE_F);
            nw = wave_shr1(carry, bnd);

            const int p0 = (wv << 6) + (c << 7);     // diag of local step 0
            float dreg[16];
#pragma unroll
            for (int u = 0; u < 16; ++u) dreg[u] = Db[read_base(p0 + u) + tid];

#pragma unroll 1
            for (int sb = 0; sb < 12; ++sb) {
#pragma unroll
                for (int u = 0; u < 16; ++u) {
                    const int s = (sb << 4) + u;     // local step; col k = s - lane
                    const float nvec = wave_shr1(cur, LARGE_F);
                    const int idx = s & 63;
                    const int hAi = __builtin_amdgcn_readlane(__float_as_int(hA), idx);
                    const int hBi = __builtin_amdgcn_readlane(__float_as_int(hB), idx);
                    const int hsi = (s & 64) ? hBi : hAi;        // uniform select
                    const float h = (haveup && s < 128) ? __int_as_float(hsi) : LARGE_F;
                    const float n = l0 ? h : nvec;               // north
                    const float w = (lane == s) ? carry : cur;   // west (k==0 sel)
                    const float mn = fminf(fminf(w, n), nw);
                    const float mx = fmaxf(fmaxf(w, n), nw);
                    const float md = __builtin_amdgcn_fmed3f(w, n, nw);
                    const float sm = mn - log2f(1.0f + exp2f(mn - md) + exp2f(mn - mx));
                    const float newc = fmaf(dreg[u], LOG2E_F, sm);
                    carry = (lane == s - 127) ? newc : carry;    // capture k==127
                    if (lane == 63)                              // export my row
                        hnd[par][wv][(s < 63) ? 1 : (s - 62)] = newc;
                    nw  = (s >= lane) ? n : nw;                  // roll after start
                    cur = newc;
                    int sp = s + 16; if (sp > 191) sp = 191;     // clamped refill
                    dreg[u] = Db[read_base(p0 + sp) + tid];
                    __builtin_amdgcn_sched_barrier(0);
                }
            }
        }
        // Phase barrier: LDS visibility only; vmcnt NOT drained.
        asm volatile("s_waitcnt lgkmcnt(0)" ::: "memory");
        __builtin_amdgcn_s_barrier();
    }
    // Wave 7 lane 63's carry after chunk 3 = R[511][511] (captured at k==127).
    if (tid == 511) out[b] = carry * LN2_F;
}

// ---------------- Fallback (only if ws too small): fused, correct, slow.
__global__ __launch_bounds__(512) void sdtw_fused_naive(const float* __restrict__ x,
                                                        const float* __restrict__ y,
                                                        float* __restrict__ out) {
    __shared__ float rbuf[3][NN];
    __shared__ float y2s[MM];
    const int b = blockIdx.x;
    const int i = threadIdx.x;

    const float* xrow  = x + ((size_t)b * NN + i) * KK;
    const float* ybase = y + (size_t)b * MM * KK;

    float xr[KK];
    float x2 = 0.f;
#pragma unroll
    for (int k = 0; k < KK; k += 4) {
        const float4 v = *(const float4*)(xrow + k);
        xr[k] = v.x; xr[k + 1] = v.y; xr[k + 2] = v.z; xr[k + 3] = v.w;
        x2 = fmaf(v.x, v.x, fmaf(v.y, v.y, fmaf(v.z, v.z, fmaf(v.w, v.w, x2))));
    }
    {
        const float* yrow = ybase + (size_t)i * KK;
        float s = 0.f;
#pragma unroll
        for (int k = 0; k < KK; k += 4) {
            const float4 v = *(const float4*)(yrow + k);
            s = fmaf(v.x, v.x, s); s = fmaf(v.y, v.y, s);
            s = fmaf(v.z, v.z, s); s = fmaf(v.w, v.w, s);
        }
        y2s[i] = s;
    }
    rbuf[0][i] = LARGE_F;
    rbuf[1][i] = LARGE_F;
    rbuf[2][i] = LARGE_F;

    float* row_w  = rbuf[0];
    float* row_p  = rbuf[2];
    float* row_p2 = rbuf[1];
    __syncthreads();

    float cur = LARGE_F;
    for (int p = 0; p < NDIAG; ++p) {
        const int j0 = p - i;
        const bool valid = (j0 >= 0) && (j0 < MM);
        float dg = 0.f;
        if (valid) {
            const float* yrow = ybase + (size_t)j0 * KK;
            float dot = 0.f;
#pragma unroll
            for (int k = 0; k < KK; k += 4) {
                const float4 v = *(const float4*)(yrow + k);
                dot = fmaf(xr[k], v.x, dot);
                dot = fmaf(xr[k + 1], v.y, dot);
                dot = fmaf(xr[k + 2], v.z, dot);
                dot = fmaf(xr[k + 3], v.w, dot);
            }
            dg = x2 + y2s[j0] - 2.f * dot;
        }
        const float r_w  = row_p[i];
        const float r_n  = (i > 0) ? row_p[i - 1] : LARGE_F;
        const float r_nw = (i > 0) ? row_p2[i - 1] : ((p == 0) ? 0.f : LARGE_F);

        const float m = fminf(fminf(r_nw, r_n), r_w);
        const float s = __expf(m - r_nw) + __expf(m - r_n) + __expf(m - r_w);
        const float softmin = m - __logf(s);

        cur = valid ? (dg + softmin) : LARGE_F;
        row_w[i] = cur;
        __syncthreads();

        float* tmp = row_w;
        row_w = row_p2; row_p2 = row_p; row_p = tmp;
    }
    if (i == NN - 1) out[b] = cur;
}

extern "C" void kernel_launch(void* const* d_in, const int* in_sizes, int n_in,
                              void* d_out, int out_size, void* d_ws, size_t ws_size,
                              hipStream_t stream) {
    const float* x = (const float*)d_in[0];
    const float* y = (const float*)d_in[1];
    float* out = (float*)d_out;

    const size_t need = (size_t)BB * PCELLS * sizeof(float);  // 135,004,160 B
    if (ws_size >= need) {
        float* Dws = (float*)d_ws;
        sdtw_dist<<<dim3(64, BB), 256, 0, stream>>>(x, y, Dws);
        sdtw_dp<<<dim3(BB), 512, 0, stream>>>(Dws, out);
    } else {
        sdtw_fused_naive<<<dim3(BB), 512, 0, stream>>>(x, y, out);
    }
}

// Round 10
// 319.416 us; speedup vs baseline: 1.6408x; 1.6408x over previous
//
#include <hip/hip_runtime.h>

#define LARGE_F 1e30f
#define LOG2E_F 1.4426950408889634f
#define LN2_F   0.6931471805599453f

constexpr int BB = 128;
constexpr int NN = 512;
constexpr int MM = 512;
constexpr int KK = 64;
constexpr int NDIAG = NN + MM - 1;   // 1023
constexpr int PCELLS = 263680;       // padded (4-float-aligned) cells per batch

// ---- 4-float-aligned antidiagonal slot layout -------------------------------
__device__ __forceinline__ int slot_off(int p) {
    if (p < NN) { const int a = p >> 2, r = p & 3; return ((a + 1) * (2 * a + r)) << 2; }
    const int t = p - NN, a = t >> 2, r = t & 3;
    return 132096 + (t << 9) - ((a * (2 * a + r - 1)) << 2);
}
__device__ __forceinline__ int imin4(int p) {
    return (p < NN) ? 0 : ((p - (NN - 1)) & ~3);
}
__device__ __forceinline__ int read_base(int p) { return slot_off(p) - imin4(p); }

// lane i <- lane i-1 via DPP wave_shr:1 (VALU). Lane 0 receives `bound`.
__device__ __forceinline__ float wave_shr1(float v, float bound) {
    const int r = __builtin_amdgcn_update_dpp(__float_as_int(bound), __float_as_int(v),
                                              0x138, 0xf, 0xf, false);
    return __int_as_float(r);
}

// ---------------- Phase 1: D[b,i,j] = ||x_i - y_j||^2 into aligned diag slots.
__global__ __launch_bounds__(256, 4) void sdtw_dist(const float* __restrict__ x,
                                                    const float* __restrict__ y,
                                                    float* __restrict__ Dws) {
    __shared__ float xs[64][68];
    __shared__ float ys[64][68];
    __shared__ float x2s[64];
    __shared__ float y2s[64];
    float (*dt)[66] = (float (*)[66])(&xs[0][0]);   // alias after k-loop

    const int b  = blockIdx.y;
    const int ti = (blockIdx.x >> 3) << 6;
    const int tj = (blockIdx.x & 7) << 6;
    const int t  = threadIdx.x;

    const float* xb = x + ((size_t)b * NN + ti) * KK;
    const float* yb = y + ((size_t)b * MM + tj) * KK;

    {
        const int r0 = t >> 4;
        const int c0 = (t & 15) << 2;
#pragma unroll
        for (int q = 0; q < 4; ++q) {
            const int r = r0 + (q << 4);
            const float4 xv = *(const float4*)(xb + r * KK + c0);
            const float4 yv = *(const float4*)(yb + r * KK + c0);
            *(float4*)(&xs[r][c0]) = xv;
            *(float4*)(&ys[r][c0]) = yv;
        }
    }
    __syncthreads();

    if (t < 128) {
        const int r = t & 63;
        const float* row = (t < 64) ? &xs[r][0] : &ys[r][0];
        float s = 0.f;
#pragma unroll
        for (int k = 0; k < KK; k += 4) {
            const float4 v = *(const float4*)(row + k);
            s = fmaf(v.x, v.x, s); s = fmaf(v.y, v.y, s);
            s = fmaf(v.z, v.z, s); s = fmaf(v.w, v.w, s);
        }
        if (t < 64) x2s[r] = s; else y2s[r] = s;
    }
    __syncthreads();

    const int ty = t >> 4;
    const int tx = t & 15;

    float acc[4][4] = {};
    for (int k0 = 0; k0 < KK; k0 += 4) {
        float4 xa[4], yv[4];
#pragma unroll
        for (int a = 0; a < 4; ++a) xa[a] = *(const float4*)(&xs[(a << 4) + ty][k0]);
#pragma unroll
        for (int c = 0; c < 4; ++c) yv[c] = *(const float4*)(&ys[(c << 4) + tx][k0]);
#pragma unroll
        for (int a = 0; a < 4; ++a) {
#pragma unroll
            for (int c = 0; c < 4; ++c) {
                acc[a][c] = fmaf(xa[a].x, yv[c].x, acc[a][c]);
                acc[a][c] = fmaf(xa[a].y, yv[c].y, acc[a][c]);
                acc[a][c] = fmaf(xa[a].z, yv[c].z, acc[a][c]);
                acc[a][c] = fmaf(xa[a].w, yv[c].w, acc[a][c]);
            }
        }
    }
    __syncthreads();

#pragma unroll
    for (int a = 0; a < 4; ++a) {
        const float xx = x2s[(a << 4) + ty];
#pragma unroll
        for (int c = 0; c < 4; ++c) {
            dt[(a << 4) + ty][(c << 4) + tx] = xx + y2s[(c << 4) + tx] - 2.f * acc[a][c];
        }
    }
    __syncthreads();

    {
        const int w    = t >> 6;
        const int lane = t & 63;
        float* Db = Dws + (size_t)b * PCELLS;
        for (int q = w; q < 127; q += 4) {
            const int i_lo = (q > 63) ? (q - 63) : 0;
            const int i_hi = (q < 63) ? q : 63;
            const int len  = i_hi - i_lo + 1;
            if (lane < len) {
                const int il = i_lo + lane;
                const int p  = ti + tj + q;
                Db[slot_off(p) + (ti + il) - imin4(p)] = dt[il][q - il];
            }
        }
    }
}

// ---------------- Phase 2: diagonal-band skewed pipeline. Thread i owns row i
// (round-8 dataflow). Wave wv processes diagonal band k = [16k,16k+16) during
// epoch e = wv + k; wave wv-1 produced the needed boundary row one epoch
// earlier -> 16-float LDS handoff (mod-3 buffers), ONE raw barrier per epoch
// (71 barriers vs 1023). Inside a band: all-register steps (DPP neighbor,
// readlane boundary, no LDS/barrier in the chain). D via per-step register
// ring refill, 16-step prefetch distance; raw barriers never drain vmcnt.
__global__ __launch_bounds__(512, 1) void sdtw_dp(const float* __restrict__ Dws,
                                                  float* __restrict__ out) {
    __shared__ float hnd[3][8][16];      // [epoch%3][producer wave][u]
    const int b    = blockIdx.x;
    const int tid  = threadIdx.x;        // row
    const int lane = tid & 63;
    const int wv   = tid >> 6;
    const float* __restrict__ Db = Dws + (size_t)b * PCELLS;
    const bool haveup = (wv > 0);

    float cur = LARGE_F;                       // R_{p-1}[tid]
    float nw  = (tid == 0) ? 0.f : LARGE_F;    // R_{p-2}[tid-1]; corner (0,0)=0
    float res = 0.f;
    float dreg[16];
#pragma unroll
    for (int u = 0; u < 16; ++u) dreg[u] = Db[read_base(u) + tid];  // band 0

    int m0 = 0, m1 = 2, m2 = 1;                // e%3, (e-1)%3, (e-2)%3
#pragma unroll 1
    for (int e = 0; e < 71; ++e) {
        const int k = e - wv;                  // my band this epoch
        if (0 <= k && k < 64) {
            const int P0 = k << 4;
            float hband = LARGE_F, hl = LARGE_F;
            if (haveup) {
                hband = hnd[m1][wv - 1][lane & 15];      // diags P0..P0+15 above
                if (k > 0) hl = hnd[m2][wv - 1][15];     // diag P0-1 above
            }
#pragma unroll
            for (int u = 0; u < 16; ++u) {
                const int p = P0 + u;
                const float nvec = wave_shr1(cur, LARGE_F);   // row above (in-wave)
                float hu;
                if (u == 0) hu = hl;
                else hu = __int_as_float(
                        __builtin_amdgcn_readlane(__float_as_int(hband), u - 1));
                const float n  = (haveup && lane == 0) ? hu : nvec;
                const float mn = fminf(fminf(cur, n), nw);
                const float mx = fmaxf(fmaxf(cur, n), nw);
                const float md = __builtin_amdgcn_fmed3f(cur, n, nw);
                const float sm = mn - log2f(1.0f + exp2f(mn - md) + exp2f(mn - mx));
                const float newc = fmaf(dreg[u], LOG2E_F, sm);
                if (lane == 63) hnd[m0][wv][u] = newc;        // export boundary
                if (p == 1022) res = newc;                    // cell (511,511)
                nw = n; cur = newc;
                int pc = p + 16; if (pc > 1022) pc = 1022;    // refill band k+1
                dreg[u] = Db[read_base(pc) + tid];
            }
        }
        { const int t3 = m2; m2 = m1; m1 = m0; m0 = t3; }
        // Epoch barrier: LDS visibility only; vmcnt NOT drained.
        asm volatile("s_waitcnt lgkmcnt(0)" ::: "memory");
        __builtin_amdgcn_s_barrier();
    }
    if (tid == 511) out[b] = res * LN2_F;
}

// ---------------- Fallback (only if ws too small): fused, correct, slow.
__global__ __launch_bounds__(512) void sdtw_fused_naive(const float* __restrict__ x,
                                                        const float* __restrict__ y,
                                                        float* __restrict__ out) {
    __shared__ float rbuf[3][NN];
    __shared__ float y2s[MM];
    const int b = blockIdx.x;
    const int i = threadIdx.x;

    const float* xrow  = x + ((size_t)b * NN + i) * KK;
    const float* ybase = y + (size_t)b * MM * KK;

    float xr[KK];
    float x2 = 0.f;
#pragma unroll
    for (int k = 0; k < KK; k += 4) {
        const float4 v = *(const float4*)(xrow + k);
        xr[k] = v.x; xr[k + 1] = v.y; xr[k + 2] = v.z; xr[k + 3] = v.w;
        x2 = fmaf(v.x, v.x, fmaf(v.y, v.y, fmaf(v.z, v.z, fmaf(v.w, v.w, x2))));
    }
    {
        const float* yrow = ybase + (size_t)i * KK;
        float s = 0.f;
#pragma unroll
        for (int k = 0; k < KK; k += 4) {
            const float4 v = *(const float4*)(yrow + k);
            s = fmaf(v.x, v.x, s); s = fmaf(v.y, v.y, s);
            s = fmaf(v.z, v.z, s); s = fmaf(v.w, v.w, s);
        }
        y2s[i] = s;
    }
    rbuf[0][i] = LARGE_F;
    rbuf[1][i] = LARGE_F;
    rbuf[2][i] = LARGE_F;

    float* row_w  = rbuf[0];
    float* row_p  = rbuf[2];
    float* row_p2 = rbuf[1];
    __syncthreads();

    float cur = LARGE_F;
    for (int p = 0; p < NDIAG; ++p) {
        const int j0 = p - i;
        const bool valid = (j0 >= 0) && (j0 < MM);
        float dg = 0.f;
        if (valid) {
            const float* yrow = ybase + (size_t)j0 * KK;
            float dot = 0.f;
#pragma unroll
            for (int k = 0; k < KK; k += 4) {
                const float4 v = *(const float4*)(yrow + k);
                dot = fmaf(xr[k], v.x, dot);
                dot = fmaf(xr[k + 1], v.y, dot);
                dot = fmaf(xr[k + 2], v.z, dot);
                dot = fmaf(xr[k + 3], v.w, dot);
            }
            dg = x2 + y2s[j0] - 2.f * dot;
        }
        const float r_w  = row_p[i];
        const float r_n  = (i > 0) ? row_p[i - 1] : LARGE_F;
        const float r_nw = (i > 0) ? row_p2[i - 1] : ((p == 0) ? 0.f : LARGE_F);

        const float m = fminf(fminf(r_nw, r_n), r_w);
        const float s = __expf(m - r_nw) + __expf(m - r_n) + __expf(m - r_w);
        const float softmin = m - __logf(s);

        cur = valid ? (dg + softmin) : LARGE_F;
        row_w[i] = cur;
        __syncthreads();

        float* tmp = row_w;
        row_w = row_p2; row_p2 = row_p; row_p = tmp;
    }
    if (i == NN - 1) out[b] = cur;
}

extern "C" void kernel_launch(void* const* d_in, const int* in_sizes, int n_in,
                              void* d_out, int out_size, void* d_ws, size_t ws_size,
                              hipStream_t stream) {
    const float* x = (const float*)d_in[0];
    const float* y = (const float*)d_in[1];
    float* out = (float*)d_out;

    const size_t need = (size_t)BB * PCELLS * sizeof(float);  // 135,004,160 B
    if (ws_size >= need) {
        float* Dws = (float*)d_ws;
        sdtw_dist<<<dim3(64, BB), 256, 0, stream>>>(x, y, Dws);
        sdtw_dp<<<dim3(BB), 512, 0, stream>>>(Dws, out);
    } else {
        sdtw_fused_naive<<<dim3(BB), 512, 0, stream>>>(x, y, out);
    }
}

// Round 11
// 215.178 us; speedup vs baseline: 2.4357x; 1.4844x over previous
//
#include <hip/hip_runtime.h>
#include <hip/hip_bf16.h>

#define LARGE_F 1e30f
#define LOG2E_F 1.4426950408889634f
#define LN2_F   0.6931471805599453f

constexpr int BB = 128;
constexpr int NN = 512;
constexpr int MM = 512;
constexpr int KK = 64;
// D layout: bf16, offset = 512*i + p  (p = i+j). Row i occupies [512i+i, 512i+i+511].
constexpr int PBATCH = 262656;              // shorts per batch (525,312 B, 16B-aligned)
constexpr size_t NEED = (size_t)BB * PBATCH * 2 + 4096;  // + slop for band-64 overshoot

// lane i <- lane i-1 via DPP wave_shr:1 (VALU). Lane 0 receives `bound`.
__device__ __forceinline__ float wave_shr1(float v, float bound) {
    const int r = __builtin_amdgcn_update_dpp(__float_as_int(bound), __float_as_int(v),
                                              0x138, 0xf, 0xf, false);
    return __int_as_float(r);
}

// ---------------- Phase 1: D[i][p] = ||x_i - y_j||^2 * log2e  (bf16, p=i+j).
// 128x128 tile, 8x8 microtile (halves LDS reads/FMA vs 4x4). Epilogue stages
// bf16 tile in LDS, then per-row contiguous b16 stores (alignment-proof).
__global__ __launch_bounds__(256, 2) void sdtw_dist(const float* __restrict__ x,
                                                    const float* __restrict__ y,
                                                    unsigned short* __restrict__ Dws) {
    __shared__ __align__(16) float xs[128][68];
    __shared__ __align__(16) float ys[128][68];
    __shared__ float x2s[128];
    __shared__ float y2s[128];
    unsigned short (*dt)[132] = (unsigned short (*)[132])(&xs[0][0]);  // 33792B <= 34816B

    const int b  = blockIdx.y;
    const int ti = (blockIdx.x >> 2) << 7;
    const int tj = (blockIdx.x & 3) << 7;
    const int t  = threadIdx.x;

    const float* xb = x + ((size_t)b * NN + ti) * KK;
    const float* yb = y + ((size_t)b * MM + tj) * KK;

    {   // stage 128x64 tiles (coalesced float4)
        const int r0 = t >> 4;
        const int c0 = (t & 15) << 2;
#pragma unroll
        for (int q = 0; q < 8; ++q) {
            const int r = r0 + (q << 4);
            *(float4*)(&xs[r][c0]) = *(const float4*)(xb + r * KK + c0);
            *(float4*)(&ys[r][c0]) = *(const float4*)(yb + r * KK + c0);
        }
    }
    __syncthreads();

    {   // row squared norms
        const int r = t & 127;
        const float* row = (t < 128) ? &xs[r][0] : &ys[r][0];
        float s = 0.f;
#pragma unroll
        for (int k = 0; k < KK; k += 4) {
            const float4 v = *(const float4*)(row + k);
            s = fmaf(v.x, v.x, s); s = fmaf(v.y, v.y, s);
            s = fmaf(v.z, v.z, s); s = fmaf(v.w, v.w, s);
        }
        if (t < 128) x2s[r] = s; else y2s[r] = s;
    }
    __syncthreads();

    const int ty = t >> 4;   // 0..15
    const int tx = t & 15;   // 0..15

    float acc[8][8] = {};
    for (int k0 = 0; k0 < KK; k0 += 4) {
        float4 xa[8], yv[8];
#pragma unroll
        for (int a = 0; a < 8; ++a) xa[a] = *(const float4*)(&xs[(a << 4) + ty][k0]);
#pragma unroll
        for (int c = 0; c < 8; ++c) yv[c] = *(const float4*)(&ys[(c << 4) + tx][k0]);
#pragma unroll
        for (int a = 0; a < 8; ++a) {
#pragma unroll
            for (int c = 0; c < 8; ++c) {
                acc[a][c] = fmaf(xa[a].x, yv[c].x, acc[a][c]);
                acc[a][c] = fmaf(xa[a].y, yv[c].y, acc[a][c]);
                acc[a][c] = fmaf(xa[a].z, yv[c].z, acc[a][c]);
                acc[a][c] = fmaf(xa[a].w, yv[c].w, acc[a][c]);
            }
        }
    }
    __syncthreads();   // xs dead -> alias as dt

#pragma unroll
    for (int a = 0; a < 8; ++a) {
        const float xx = x2s[(a << 4) + ty];
#pragma unroll
        for (int c = 0; c < 8; ++c) {
            const float d = (xx + y2s[(c << 4) + tx] - 2.f * acc[a][c]) * LOG2E_F;
            __hip_bfloat16 h = __float2bfloat16(d);
            dt[(a << 4) + ty][(c << 4) + tx] = *(unsigned short*)&h;
        }
    }
    __syncthreads();

    {   // write-out: row r -> D[gi][gi+tj .. +127]: contiguous 128 shorts.
        const int wv = t >> 6, lane = t & 63;
        unsigned short* Dg = Dws + (size_t)b * PBATCH;
#pragma unroll 4
        for (int r = wv; r < 128; r += 4) {
            const int gi = ti + r;
            const int base = 512 * gi + (gi + tj);    // offset of col tj
            Dg[base + lane]      = dt[r][lane];
            Dg[base + lane + 64] = dt[r][lane + 64];
        }
    }
}

// ---------------- Phase 2: band-pipelined DP, 256 threads (4 waves), thread t
// owns rows 2t,2t+1. Wave wv does 16-diag band k at epoch e=wv+k; one raw
// barrier per epoch (68 total). Per band: 4 uint4 loads (32B/row contiguous in
// the (row,diag) layout) -> real register prefetch (sched_barrier-pinned);
// 16 all-register steps (DPP neighbor, readlane boundary). Invalid cells
// self-propagate LARGE / stay in never-read cols (proven rounds 8/10).
__global__ __launch_bounds__(256, 1) void sdtw_dp(const unsigned short* __restrict__ Dws,
                                                  float* __restrict__ out) {
    __shared__ __align__(16) float hnd[3][4][16];
    const int b    = blockIdx.x;
    const int t    = threadIdx.x;
    const int lane = t & 63;
    const int wv   = t >> 6;

    if (t < 192) ((float*)hnd)[t] = LARGE_F;
    __syncthreads();

    const char* Dbase = (const char*)Dws;
    unsigned off = (unsigned)b * 525312u + (unsigned)t * 2048u;  // row 2t, band 0

    // State: curA/curB = R_{p-1}[2t]/[2t+1]; oldA = R_{p-2}[2t]; nwA = R_{p-2}[2t-1].
    float curA = LARGE_F, curB = LARGE_F, oldA = LARGE_F;
    float nwA  = (t == 0) ? 0.f : LARGE_F;   // corner (0,0)
    float res  = 0.f;
    float hband_prev = LARGE_F;

    uint4 ca0, ca1, cb0, cb1;                // current band D (rows a,b; 32B each)
    ca0 = *(const uint4*)(Dbase + off);
    ca1 = *(const uint4*)(Dbase + off + 16);
    cb0 = *(const uint4*)(Dbase + off + 1024);
    cb1 = *(const uint4*)(Dbase + off + 1040);
    off += 32;

    int m0 = 0, m1 = 2;                      // e%3, (e-1)%3
#pragma unroll 1
    for (int e = 0; e < 68; ++e) {
        const int k = e - wv;
        if (0 <= k && k < 64) {
            // Unpack current band into scalars (frees ca for the prefetch).
            const unsigned qa[8] = {ca0.x, ca0.y, ca0.z, ca0.w, ca1.x, ca1.y, ca1.z, ca1.w};
            const unsigned qb[8] = {cb0.x, cb0.y, cb0.z, cb0.w, cb1.x, cb1.y, cb1.z, cb1.w};
            float dA[16], dB[16];
#pragma unroll
            for (int u = 0; u < 16; ++u) {
                const unsigned wa = qa[u >> 1], wb = qb[u >> 1];
                dA[u] = __uint_as_float((u & 1) ? (wa & 0xffff0000u) : (wa << 16));
                dB[u] = __uint_as_float((u & 1) ? (wb & 0xffff0000u) : (wb << 16));
            }
            // Prefetch band k+1 (k=63 overshoots into the +4KB ws slop; unused).
            ca0 = *(const uint4*)(Dbase + off);
            ca1 = *(const uint4*)(Dbase + off + 16);
            cb0 = *(const uint4*)(Dbase + off + 1024);
            cb1 = *(const uint4*)(Dbase + off + 1040);
            off += 32;
            __builtin_amdgcn_sched_barrier(0);   // pin loads before compute

            // Boundary row (128wv-1) values for this band, from wave above.
            const float hband = hnd[m1][(wv > 0) ? (wv - 1) : 0][lane & 15];
            float h[16];
#pragma unroll
            for (int u = 0; u < 16; ++u) {
                const float nvec = wave_shr1(curB, LARGE_F);   // thread t-1's curB
                const float hu = __int_as_float(__builtin_amdgcn_readlane(
                    __float_as_int((u == 0) ? hband_prev : hband), (u == 0) ? 15 : (u - 1)));
                const float bnd = (wv > 0) ? hu : LARGE_F;
                const float nA  = (lane == 0) ? bnd : nvec;
                // cell a: (2t, p-2t)
                const float mn = fminf(fminf(curA, nA), nwA);
                const float mx = fmaxf(fmaxf(curA, nA), nwA);
                const float md = __builtin_amdgcn_fmed3f(curA, nA, nwA);
                const float newA = dA[u] + (mn - log2f(1.f + exp2f(mn - md) + exp2f(mn - mx)));
                // cell b: (2t+1, p-2t-1): west curB, north curA(old), nw oldA
                const float mn2 = fminf(fminf(curB, curA), oldA);
                const float mx2 = fmaxf(fmaxf(curB, curA), oldA);
                const float md2 = __builtin_amdgcn_fmed3f(curB, curA, oldA);
                const float newB = dB[u] + (mn2 - log2f(1.f + exp2f(mn2 - md2) + exp2f(mn2 - mx2)));
                h[u] = newB;
                if (16 * k + u == 1022) res = newB;   // cell (511,511) at t==255
                nwA = nA; oldA = curA; curA = newA; curB = newB;
            }
            hband_prev = hband;
            if (lane == 63) {   // batch-export my bottom row (row 128wv+127)
                *(float4*)(&hnd[m0][wv][0])  = make_float4(h[0], h[1], h[2], h[3]);
                *(float4*)(&hnd[m0][wv][4])  = make_float4(h[4], h[5], h[6], h[7]);
                *(float4*)(&hnd[m0][wv][8])  = make_float4(h[8], h[9], h[10], h[11]);
                *(float4*)(&hnd[m0][wv][12]) = make_float4(h[12], h[13], h[14], h[15]);
            }
        }
        // Epoch barrier: LDS visibility only; vmcnt NOT drained.
        asm volatile("s_waitcnt lgkmcnt(0)" ::: "memory");
        __builtin_amdgcn_s_barrier();
        m0 = (m0 == 2) ? 0 : m0 + 1;
        m1 = (m1 == 2) ? 0 : m1 + 1;
    }
    if (t == 255) out[b] = res * LN2_F;
}

// ---------------- Fallback (only if ws too small): fused, correct, slow.
__global__ __launch_bounds__(512) void sdtw_fused_naive(const float* __restrict__ x,
                                                        const float* __restrict__ y,
                                                        float* __restrict__ out) {
    __shared__ float rbuf[3][NN];
    __shared__ float y2s[MM];
    const int b = blockIdx.x;
    const int i = threadIdx.x;

    const float* xrow  = x + ((size_t)b * NN + i) * KK;
    const float* ybase = y + (size_t)b * MM * KK;

    float xr[KK];
    float x2 = 0.f;
#pragma unroll
    for (int k = 0; k < KK; k += 4) {
        const float4 v = *(const float4*)(xrow + k);
        xr[k] = v.x; xr[k + 1] = v.y; xr[k + 2] = v.z; xr[k + 3] = v.w;
        x2 = fmaf(v.x, v.x, fmaf(v.y, v.y, fmaf(v.z, v.z, fmaf(v.w, v.w, x2))));
    }
    {
        const float* yrow = ybase + (size_t)i * KK;
        float s = 0.f;
#pragma unroll
        for (int k = 0; k < KK; k += 4) {
            const float4 v = *(const float4*)(yrow + k);
            s = fmaf(v.x, v.x, s); s = fmaf(v.y, v.y, s);
            s = fmaf(v.z, v.z, s); s = fmaf(v.w, v.w, s);
        }
        y2s[i] = s;
    }
    rbuf[0][i] = LARGE_F;
    rbuf[1][i] = LARGE_F;
    rbuf[2][i] = LARGE_F;

    float* row_w  = rbuf[0];
    float* row_p  = rbuf[2];
    float* row_p2 = rbuf[1];
    __syncthreads();

    float cur = LARGE_F;
    for (int p = 0; p < NN + MM - 1; ++p) {
        const int j0 = p - i;
        const bool valid = (j0 >= 0) && (j0 < MM);
        float dg = 0.f;
        if (valid) {
            const float* yrow = ybase + (size_t)j0 * KK;
            float dot = 0.f;
#pragma unroll
            for (int k = 0; k < KK; k += 4) {
                const float4 v = *(const float4*)(yrow + k);
                dot = fmaf(xr[k], v.x, dot);
                dot = fmaf(xr[k + 1], v.y, dot);
                dot = fmaf(xr[k + 2], v.z, dot);
                dot = fmaf(xr[k + 3], v.w, dot);
            }
            dg = x2 + y2s[j0] - 2.f * dot;
        }
        const float r_w  = row_p[i];
        const float r_n  = (i > 0) ? row_p[i - 1] : LARGE_F;
        const float r_nw = (i > 0) ? row_p2[i - 1] : ((p == 0) ? 0.f : LARGE_F);

        const float m = fminf(fminf(r_nw, r_n), r_w);
        const float s = __expf(m - r_nw) + __expf(m - r_n) + __expf(m - r_w);
        const float softmin = m - __logf(s);

        cur = valid ? (dg + softmin) : LARGE_F;
        row_w[i] = cur;
        __syncthreads();

        float* tmp = row_w;
        row_w = row_p2; row_p2 = row_p; row_p = tmp;
    }
    if (i == NN - 1) out[b] = cur;
}

extern "C" void kernel_launch(void* const* d_in, const int* in_sizes, int n_in,
                              void* d_out, int out_size, void* d_ws, size_t ws_size,
                              hipStream_t stream) {
    const float* x = (const float*)d_in[0];
    const float* y = (const float*)d_in[1];
    float* out = (float*)d_out;

    if (ws_size >= NEED) {   // 67,244,032 B (known ws >= 135 MB from prior rounds)
        unsigned short* Dws = (unsigned short*)d_ws;
        sdtw_dist<<<dim3(16, BB), 256, 0, stream>>>(x, y, Dws);
        sdtw_dp<<<dim3(BB), 256, 0, stream>>>(Dws, out);
    } else {
        sdtw_fused_naive<<<dim3(BB), 512, 0, stream>>>(x, y, out);
    }
}

// Round 12
// 200.305 us; speedup vs baseline: 2.6166x; 1.0743x over previous
//
#include <hip/hip_runtime.h>
#include <hip/hip_bf16.h>

#define LARGE_F 1e30f
#define LOG2E_F 1.4426950408889634f
#define LN2_F   0.6931471805599453f

constexpr int BB = 128;
constexpr int NN = 512;
constexpr int MM = 512;
constexpr int KK = 64;
// D layout: bf16, offset = 512*i + p  (p = i+j). Row i occupies [513i, 513i+511].
constexpr int PBATCH = 262656;              // shorts per batch (525,312 B, 16B-aligned)
constexpr size_t NEED = (size_t)BB * PBATCH * 2 + 4096;  // + slop for band-64 overshoot

// lane i <- lane i-1 via DPP wave_shr:1 (VALU). Lane 0 receives `bound`.
__device__ __forceinline__ float wave_shr1(float v, float bound) {
    const int r = __builtin_amdgcn_update_dpp(__float_as_int(bound), __float_as_int(v),
                                              0x138, 0xf, 0xf, false);
    return __int_as_float(r);
}

// ---------------- Phase 1: D[i][p] = ||x_i - y_j||^2 * log2e  (bf16, p=i+j).
// 128x128 tile, 8x8 microtile. Epilogue stages bf16 tile in LDS, then per-row
// contiguous b16 stores.
__global__ __launch_bounds__(256, 2) void sdtw_dist(const float* __restrict__ x,
                                                    const float* __restrict__ y,
                                                    unsigned short* __restrict__ Dws) {
    __shared__ __align__(16) float xs[128][68];
    __shared__ __align__(16) float ys[128][68];
    __shared__ float x2s[128];
    __shared__ float y2s[128];
    unsigned short (*dt)[132] = (unsigned short (*)[132])(&xs[0][0]);  // 33792B

    const int b  = blockIdx.y;
    const int ti = (blockIdx.x >> 2) << 7;
    const int tj = (blockIdx.x & 3) << 7;
    const int t  = threadIdx.x;

    const float* xb = x + ((size_t)b * NN + ti) * KK;
    const float* yb = y + ((size_t)b * MM + tj) * KK;

    {   // stage 128x64 tiles (coalesced float4)
        const int r0 = t >> 4;
        const int c0 = (t & 15) << 2;
#pragma unroll
        for (int q = 0; q < 8; ++q) {
            const int r = r0 + (q << 4);
            *(float4*)(&xs[r][c0]) = *(const float4*)(xb + r * KK + c0);
            *(float4*)(&ys[r][c0]) = *(const float4*)(yb + r * KK + c0);
        }
    }
    __syncthreads();

    {   // row squared norms
        const int r = t & 127;
        const float* row = (t < 128) ? &xs[r][0] : &ys[r][0];
        float s = 0.f;
#pragma unroll
        for (int k = 0; k < KK; k += 4) {
            const float4 v = *(const float4*)(row + k);
            s = fmaf(v.x, v.x, s); s = fmaf(v.y, v.y, s);
            s = fmaf(v.z, v.z, s); s = fmaf(v.w, v.w, s);
        }
        if (t < 128) x2s[r] = s; else y2s[r] = s;
    }
    __syncthreads();

    const int ty = t >> 4;   // 0..15
    const int tx = t & 15;   // 0..15

    float acc[8][8] = {};
    for (int k0 = 0; k0 < KK; k0 += 4) {
        float4 xa[8], yv[8];
#pragma unroll
        for (int a = 0; a < 8; ++a) xa[a] = *(const float4*)(&xs[(a << 4) + ty][k0]);
#pragma unroll
        for (int c = 0; c < 8; ++c) yv[c] = *(const float4*)(&ys[(c << 4) + tx][k0]);
#pragma unroll
        for (int a = 0; a < 8; ++a) {
#pragma unroll
            for (int c = 0; c < 8; ++c) {
                acc[a][c] = fmaf(xa[a].x, yv[c].x, acc[a][c]);
                acc[a][c] = fmaf(xa[a].y, yv[c].y, acc[a][c]);
                acc[a][c] = fmaf(xa[a].z, yv[c].z, acc[a][c]);
                acc[a][c] = fmaf(xa[a].w, yv[c].w, acc[a][c]);
            }
        }
    }
    __syncthreads();   // xs dead -> alias as dt

#pragma unroll
    for (int a = 0; a < 8; ++a) {
        const float xx = x2s[(a << 4) + ty];
#pragma unroll
        for (int c = 0; c < 8; ++c) {
            const float d = (xx + y2s[(c << 4) + tx] - 2.f * acc[a][c]) * LOG2E_F;
            __hip_bfloat16 h = __float2bfloat16(d);
            dt[(a << 4) + ty][(c << 4) + tx] = *(unsigned short*)&h;
        }
    }
    __syncthreads();

    {   // write-out: row r -> D[gi][gi+tj .. +127]: contiguous 128 shorts.
        const int wv = t >> 6, lane = t & 63;
        unsigned short* Dg = Dws + (size_t)b * PBATCH;
#pragma unroll 4
        for (int r = wv; r < 128; r += 4) {
            const int gi = ti + r;
            const int base = 512 * gi + (gi + tj);
            Dg[base + lane]      = dt[r][lane];
            Dg[base + lane + 64] = dt[r][lane + 64];
        }
    }
}

// ---------------- Phase 2: band-pipelined DP, 512 threads (8 waves = 2/SIMD),
// thread tid owns row tid. Wave wv does 16-diag band k at epoch e = wv + k;
// one raw barrier per epoch (71 total). Per band: 2 uint4 loads (32B/row,
// contiguous bf16) -> register prefetch pinned by sched_barrier(0); 16
// all-register steps (DPP neighbor, readlane boundary). 2 waves/SIMD so the
// second wave's issue fills the softmin chain/trans stalls (the round-11
// single-wave-per-SIMD limit). Garbage cells self-propagate LARGE (proven
// rounds 8-11: out-of-range D reads are finite small bf16 values).
__global__ __launch_bounds__(512, 1) void sdtw_dp(const unsigned short* __restrict__ Dws,
                                                  float* __restrict__ out) {
    __shared__ __align__(16) float hnd[3][8][16];
    const int b    = blockIdx.x;
    const int tid  = threadIdx.x;        // row
    const int lane = tid & 63;
    const int wv   = tid >> 6;

    if (tid < 384) ((float*)hnd)[tid] = LARGE_F;
    __syncthreads();

    const char* Dbase = (const char*)Dws;
    unsigned off = (unsigned)b * 525312u + (unsigned)tid * 1024u;  // row tid, band 0

    float cur = LARGE_F;                     // R_{p-1}[tid]
    float nw  = (tid == 0) ? 0.f : LARGE_F;  // R_{p-2}[tid-1]; corner (0,0)=0
    float res = 0.f;
    float hband_prev = LARGE_F;
    const bool haveup = (wv > 0);
    const bool l0     = (lane == 0);

    uint4 c0 = *(const uint4*)(Dbase + off);
    uint4 c1 = *(const uint4*)(Dbase + off + 16);
    off += 32;

    int m0 = 0, m1 = 2;                      // e%3, (e-1)%3
#pragma unroll 1
    for (int e = 0; e < 71; ++e) {
        const int k = e - wv;
        if (0 <= k && k < 64) {
            // Unpack current band (frees c0/c1 for the prefetch).
            const unsigned q[8] = {c0.x, c0.y, c0.z, c0.w, c1.x, c1.y, c1.z, c1.w};
            float d[16];
#pragma unroll
            for (int u = 0; u < 16; ++u) {
                const unsigned w_ = q[u >> 1];
                d[u] = __uint_as_float((u & 1) ? (w_ & 0xffff0000u) : (w_ << 16));
            }
            // Prefetch band k+1 (k=63 overshoots into the +4KB ws slop; unused).
            c0 = *(const uint4*)(Dbase + off);
            c1 = *(const uint4*)(Dbase + off + 16);
            off += 32;
            __builtin_amdgcn_sched_barrier(0);   // pin loads before compute

            // Boundary row (64wv-1) band values from the wave above.
            const float hband = haveup ? hnd[m1][wv - 1][lane & 15] : LARGE_F;
            float h[16];
#pragma unroll
            for (int u = 0; u < 16; ++u) {
                const float nvec = wave_shr1(cur, LARGE_F);   // row above, in-wave
                const float hu = __int_as_float(__builtin_amdgcn_readlane(
                    __float_as_int((u == 0) ? hband_prev : hband),
                    (u == 0) ? 15 : (u - 1)));
                const float n  = (haveup && l0) ? hu : nvec;
                const float mn = fminf(fminf(cur, n), nw);
                const float mx = fmaxf(fmaxf(cur, n), nw);
                const float md = __builtin_amdgcn_fmed3f(cur, n, nw);
                const float sm = mn - log2f(1.f + exp2f(mn - md) + exp2f(mn - mx));
                const float newc = d[u] + sm;
                h[u] = newc;
                if (u == 14) { if (k == 63) res = newc; }     // cell (511,511)
                nw = n; cur = newc;
            }
            hband_prev = hband;
            if (lane == 63) {   // batch-export my row (row 64wv+63) for this band
                *(float4*)(&hnd[m0][wv][0])  = make_float4(h[0], h[1], h[2], h[3]);
                *(float4*)(&hnd[m0][wv][4])  = make_float4(h[4], h[5], h[6], h[7]);
                *(float4*)(&hnd[m0][wv][8])  = make_float4(h[8], h[9], h[10], h[11]);
                *(float4*)(&hnd[m0][wv][12]) = make_float4(h[12], h[13], h[14], h[15]);
            }
        }
        // Epoch barrier: LDS visibility only; vmcnt NOT drained.
        asm volatile("s_waitcnt lgkmcnt(0)" ::: "memory");
        __builtin_amdgcn_s_barrier();
        m0 = (m0 == 2) ? 0 : m0 + 1;
        m1 = (m1 == 2) ? 0 : m1 + 1;
    }
    if (tid == 511) out[b] = res * LN2_F;
}

// ---------------- Fallback (only if ws too small): fused, correct, slow.
__global__ __launch_bounds__(512) void sdtw_fused_naive(const float* __restrict__ x,
                                                        const float* __restrict__ y,
                                                        float* __restrict__ out) {
    __shared__ float rbuf[3][NN];
    __shared__ float y2s[MM];
    const int b = blockIdx.x;
    const int i = threadIdx.x;

    const float* xrow  = x + ((size_t)b * NN + i) * KK;
    const float* ybase = y + (size_t)b * MM * KK;

    float xr[KK];
    float x2 = 0.f;
#pragma unroll
    for (int k = 0; k < KK; k += 4) {
        const float4 v = *(const float4*)(xrow + k);
        xr[k] = v.x; xr[k + 1] = v.y; xr[k + 2] = v.z; xr[k + 3] = v.w;
        x2 = fmaf(v.x, v.x, fmaf(v.y, v.y, fmaf(v.z, v.z, fmaf(v.w, v.w, x2))));
    }
    {
        const float* yrow = ybase + (size_t)i * KK;
        float s = 0.f;
#pragma unroll
        for (int k = 0; k < KK; k += 4) {
            const float4 v = *(const float4*)(yrow + k);
            s = fmaf(v.x, v.x, s); s = fmaf(v.y, v.y, s);
            s = fmaf(v.z, v.z, s); s = fmaf(v.w, v.w, s);
        }
        y2s[i] = s;
    }
    rbuf[0][i] = LARGE_F;
    rbuf[1][i] = LARGE_F;
    rbuf[2][i] = LARGE_F;

    float* row_w  = rbuf[0];
    float* row_p  = rbuf[2];
    float* row_p2 = rbuf[1];
    __syncthreads();

    float cur = LARGE_F;
    for (int p = 0; p < NN + MM - 1; ++p) {
        const int j0 = p - i;
        const bool valid = (j0 >= 0) && (j0 < MM);
        float dg = 0.f;
        if (valid) {
            const float* yrow = ybase + (size_t)j0 * KK;
            float dot = 0.f;
#pragma unroll
            for (int k = 0; k < KK; k += 4) {
                const float4 v = *(const float4*)(yrow + k);
                dot = fmaf(xr[k], v.x, dot);
                dot = fmaf(xr[k + 1], v.y, dot);
                dot = fmaf(xr[k + 2], v.z, dot);
                dot = fmaf(xr[k + 3], v.w, dot);
            }
            dg = x2 + y2s[j0] - 2.f * dot;
        }
        const float r_w  = row_p[i];
        const float r_n  = (i > 0) ? row_p[i - 1] : LARGE_F;
        const float r_nw = (i > 0) ? row_p2[i - 1] : ((p == 0) ? 0.f : LARGE_F);

        const float m = fminf(fminf(r_nw, r_n), r_w);
        const float s = __expf(m - r_nw) + __expf(m - r_n) + __expf(m - r_w);
        const float softmin = m - __logf(s);

        cur = valid ? (dg + softmin) : LARGE_F;
        row_w[i] = cur;
        __syncthreads();

        float* tmp = row_w;
        row_w = row_p2; row_p2 = row_p; row_p = tmp;
    }
    if (i == NN - 1) out[b] = cur;
}

extern "C" void kernel_launch(void* const* d_in, const int* in_sizes, int n_in,
                              void* d_out, int out_size, void* d_ws, size_t ws_size,
                              hipStream_t stream) {
    const float* x = (const float*)d_in[0];
    const float* y = (const float*)d_in[1];
    float* out = (float*)d_out;

    if (ws_size >= NEED) {   // 67,244,032 B
        unsigned short* Dws = (unsigned short*)d_ws;
        sdtw_dist<<<dim3(16, BB), 256, 0, stream>>>(x, y, Dws);
        sdtw_dp<<<dim3(BB), 512, 0, stream>>>(Dws, out);
    } else {
        sdtw_fused_naive<<<dim3(BB), 512, 0, stream>>>(x, y, out);
    }
}